// Round 18
// baseline (224.068 us; speedup 1.0000x reference)
//
#include <hip/hip_runtime.h>
#include <hip/hip_bf16.h>
#include <math.h>

#define NH   8
#define NSEQ 4096
#define NB   2
#define HID  256
#define VD   32
#define RANK 409      // 0-indexed; pos = 0.1*(4096-1) = 409.5 -> lerp(s[409],s[410],0.5)
#define NBIN 128      // candidate-space histogram bins (per row)
#define CAND 704      // per-row candidate cap (mean 480, sd 20.6); multiple of 32
#define TG   0.1171875f  // raw-space threshold guess (scale>0 -> raw order == scaled order)

typedef float floatx4 __attribute__((ext_vector_type(4)));

__device__ __forceinline__ unsigned mbcnt64(unsigned long long m) {
  return __builtin_amdgcn_mbcnt_hi((unsigned)(m >> 32),
                                   __builtin_amdgcn_mbcnt_lo((unsigned)m, 0u));
}
__device__ __forceinline__ float wred_min(float x) {
#pragma unroll
  for (int d = 32; d; d >>= 1) x = fminf(x, __shfl_xor(x, d, 64));
  return x;
}
__device__ __forceinline__ float wred_max(float x) {
#pragma unroll
  for (int d = 32; d; d >>= 1) x = fmaxf(x, __shfl_xor(x, d, 64));
  return x;
}
__device__ __forceinline__ float wred_sum(float x) {
#pragma unroll
  for (int d = 32; d; d >>= 1) x += __shfl_xor(x, d, 64);
  return x;
}
__device__ __forceinline__ float gelu_tanh(float x) {
  float x3 = x * x * x;
  float inner = 0.7978845608028654f * (x + 0.044715f * x3);
  return 0.5f * x * (1.0f + tanhf(inner));
}
__device__ __forceinline__ float bflo(unsigned u) { return __uint_as_float(u << 16); }
__device__ __forceinline__ float bfhi(unsigned u) { return __uint_as_float(u & 0xFFFF0000u); }

// ---------------- kernel A: value_bf16[h][n][b*32+k] = x @ weight; + scales -

__global__ __launch_bounds__(256) void value_kernel(
    const float* __restrict__ x, const float* __restrict__ w,
    const float* __restrict__ r, __hip_bfloat16* __restrict__ value,
    float* __restrict__ scales) {
  const int tid = threadIdx.x;

  if (blockIdx.x == 0 && tid < NH) {
    double rv = (double)r[tid];
    const float c0 = (float)(0.25 * 3.141592653589793 * (1.0 - 1e-07));
    float s1 = (float)sin(rv);
    float t = c0 * (1.0f + s1);
    scales[tid] = (float)tan((double)t);
  }

  const int n0 = blockIdx.x * 8;
  __shared__ float sx[NB][8][HID];
#pragma unroll
  for (int i = 0; i < 16; i++) {
    int idx = i * 256 + tid;
    int b = idx >> 11;
    int rem = idx & 2047;
    int nn = rem >> 8;
    int j = rem & 255;
    sx[b][nn][j] = x[((size_t)b * NSEQ + n0 + nn) * HID + j];
  }
  __syncthreads();

  const int h = tid >> 5, k = tid & 31;
  float acc[NB][8];
#pragma unroll
  for (int b = 0; b < NB; b++)
#pragma unroll
    for (int nn = 0; nn < 8; nn++) acc[b][nn] = 0.f;

  const float* wp = w + (size_t)h * HID * VD + k;
  for (int j4 = 0; j4 < HID; j4 += 4) {
    float wv0 = wp[(size_t)(j4 + 0) * VD];
    float wv1 = wp[(size_t)(j4 + 1) * VD];
    float wv2 = wp[(size_t)(j4 + 2) * VD];
    float wv3 = wp[(size_t)(j4 + 3) * VD];
#pragma unroll
    for (int b = 0; b < NB; b++) {
#pragma unroll
      for (int nn = 0; nn < 8; nn++) {
        const float4 xv = *reinterpret_cast<const float4*>(&sx[b][nn][j4]);
        float a = acc[b][nn];
        a = fmaf(xv.x, wv0, a);
        a = fmaf(xv.y, wv1, a);
        a = fmaf(xv.z, wv2, a);
        a = fmaf(xv.w, wv3, a);
        acc[b][nn] = a;
      }
    }
  }
#pragma unroll
  for (int b = 0; b < NB; b++)
#pragma unroll
    for (int nn = 0; nn < 8; nn++)
      value[((size_t)h * NSEQ + n0 + nn) * (NB * VD) + b * VD + k] =
          __float2bfloat16(acc[b][nn]);
}

// ---------------- kernel B: 2 ROWS PER WAVE (dual-chain ILP), zero barriers -
// Entry byte-offset = n*128 (bf16 rows) -> (G<<15)|(lane<<9)|(elem<<7).

// parametrized: raw-space test + RAW store into SC/NC
#define PROCD(CV, G, SC, NC)                                                       \
  do {                                                                             \
    const int nb_ = ((G) << 15) | (lane << 9);                                     \
    { bool s = (CV).x <= TG; unsigned long long m = __ballot(s);                   \
      unsigned p = NC + mbcnt64(m);                                                \
      if (s && p < CAND) SC[p] = make_float2((CV).x, __int_as_float(nb_));         \
      NC += (unsigned)__popcll(m); }                                               \
    { bool s = (CV).y <= TG; unsigned long long m = __ballot(s);                   \
      unsigned p = NC + mbcnt64(m);                                                \
      if (s && p < CAND) SC[p] = make_float2((CV).y, __int_as_float(nb_ | 128));   \
      NC += (unsigned)__popcll(m); }                                               \
    { bool s = (CV).z <= TG; unsigned long long m = __ballot(s);                   \
      unsigned p = NC + mbcnt64(m);                                                \
      if (s && p < CAND) SC[p] = make_float2((CV).z, __int_as_float(nb_ | 256));   \
      NC += (unsigned)__popcll(m); }                                               \
    { bool s = (CV).w <= TG; unsigned long long m = __ballot(s);                   \
      unsigned p = NC + mbcnt64(m);                                                \
      if (s && p < CAND) SC[p] = make_float2((CV).w, __int_as_float(nb_ | 384));   \
      NC += (unsigned)__popcll(m); }                                               \
  } while (0)

// cold-path macros (names bind to sel_weight locals/params: sc, nc, scale, lane)
#define PROCR(CV, G, T)                                                            \
  do {                                                                             \
    const int nb_ = ((G) << 15) | (lane << 9);                                     \
    { bool s = (CV).x <= (T); unsigned long long m = __ballot(s);                  \
      unsigned p = nc + mbcnt64(m);                                                \
      if (s && p < CAND) sc[p] = make_float2((CV).x, __int_as_float(nb_));         \
      nc += (unsigned)__popcll(m); }                                               \
    { bool s = (CV).y <= (T); unsigned long long m = __ballot(s);                  \
      unsigned p = nc + mbcnt64(m);                                                \
      if (s && p < CAND) sc[p] = make_float2((CV).y, __int_as_float(nb_ | 128));   \
      nc += (unsigned)__popcll(m); }                                               \
    { bool s = (CV).z <= (T); unsigned long long m = __ballot(s);                  \
      unsigned p = nc + mbcnt64(m);                                                \
      if (s && p < CAND) sc[p] = make_float2((CV).z, __int_as_float(nb_ | 256));   \
      nc += (unsigned)__popcll(m); }                                               \
    { bool s = (CV).w <= (T); unsigned long long m = __ballot(s);                  \
      unsigned p = nc + mbcnt64(m);                                                \
      if (s && p < CAND) sc[p] = make_float2((CV).w, __int_as_float(nb_ | 384));   \
      nc += (unsigned)__popcll(m); }                                               \
  } while (0)

#define PROCS(CV, G, TS)                                                                  \
  do {                                                                                    \
    const int nb_ = ((G) << 15) | (lane << 9);                                            \
    { float t_ = (CV).x * scale; bool s = t_ <= (TS); unsigned long long m = __ballot(s); \
      unsigned p = nc + mbcnt64(m);                                                       \
      if (s && p < CAND) sc[p] = make_float2(t_, __int_as_float(nb_));                    \
      nc += (unsigned)__popcll(m); }                                                      \
    { float t_ = (CV).y * scale; bool s = t_ <= (TS); unsigned long long m = __ballot(s); \
      unsigned p = nc + mbcnt64(m);                                                       \
      if (s && p < CAND) sc[p] = make_float2(t_, __int_as_float(nb_ | 128));              \
      nc += (unsigned)__popcll(m); }                                                      \
    { float t_ = (CV).z * scale; bool s = t_ <= (TS); unsigned long long m = __ballot(s); \
      unsigned p = nc + mbcnt64(m);                                                       \
      if (s && p < CAND) sc[p] = make_float2(t_, __int_as_float(nb_ | 256));              \
      nc += (unsigned)__popcll(m); }                                                      \
    { float t_ = (CV).w * scale; bool s = t_ <= (TS); unsigned long long m = __ballot(s); \
      unsigned p = nc + mbcnt64(m);                                                       \
      if (s && p < CAND) sc[p] = make_float2(t_, __int_as_float(nb_ | 384));              \
      nc += (unsigned)__popcll(m); }                                                      \
  } while (0)

#define CNT1(U)                                                        \
  do {                                                                 \
    bool s_ = (U) <= Tc;                                               \
    cN += (unsigned)__popcll(__ballot(s_));                            \
    if (s_) vb = fmaxf(vb, (U)); else vs = fminf(vs, (U));             \
  } while (0)

// selection + weights for one row's candidate buffer. Returns invd and padded
// entry count (compacted, zero-filled to multiple of 32).
__device__ __forceinline__ void sel_weight(
    const floatx4* row4, const float scale, float2* sc, unsigned nc,
    unsigned* sh, float* ssm, unsigned* scn, const int lane,
    float& invd_out, unsigned& padded_out) {
  float Tsel = TG;
  bool exact = false;
  float ex409 = 0.f, ex410 = 0.f;

  if (nc < (unsigned)(RANK + 2) || nc > (unsigned)CAND) {
    // ---- cold (wave-local, ~never): count-only bisect; exact-tie on collapse
    float lo, hi;
    if (nc < (unsigned)(RANK + 2)) { lo = TG; hi = 1.0f; }
    else { lo = 0.f; hi = TG; }
    bool collapse = false, ok = false;
    for (int it = 0; it < 40; ++it) {
      float mid = 0.5f * (lo + hi);
      if (!(mid > lo && mid < hi)) { collapse = true; break; }
      unsigned cN = 0;
      float vb = -INFINITY, vs = INFINITY;
      const float Tc = mid;
#pragma unroll 2
      for (int ch = 0; ch < 16; ++ch) {
        floatx4 cv = __builtin_nontemporal_load(row4 + ch * 64);
        CNT1(cv.x); CNT1(cv.y); CNT1(cv.z); CNT1(cv.w);
      }
      if (cN >= (unsigned)(RANK + 2) && cN <= (unsigned)CAND) { Tsel = mid; ok = true; break; }
      if (cN < (unsigned)(RANK + 2)) lo = mid; else hi = mid;
    }
    if (collapse) {
      unsigned cN = 0;
      float vb = -INFINITY, vs = INFINITY;
      {
        const float Tc = lo;
#pragma unroll 2
        for (int ch = 0; ch < 16; ++ch) {
          floatx4 cv = __builtin_nontemporal_load(row4 + ch * 64);
          CNT1(cv.x); CNT1(cv.y); CNT1(cv.z); CNT1(cv.w);
        }
      }
      vb = wred_max(vb);
      vs = wred_min(vs);
      float s409r, s410r;
      if (cN >= (unsigned)(RANK + 2)) { s409r = vb; s410r = vb; }
      else if (cN == (unsigned)(RANK + 1)) { s409r = vb; s410r = vs; }
      else { s409r = vs; s410r = vs; }
      ex409 = s409r * scale;
      ex410 = s410r * scale;
      exact = true;
      float thrS = 0.5f * ex409 + 0.5f * ex410;
      nc = 0;
#pragma unroll 2
      for (int ch = 0; ch < 16; ++ch) {
        floatx4 cv = __builtin_nontemporal_load(row4 + ch * 64);
        PROCS(cv, ch, thrS);
      }
    } else if (ok) {
      nc = 0;
      const float Tf = Tsel;
#pragma unroll 2
      for (int ch = 0; ch < 16; ++ch) {
        floatx4 cv = __builtin_nontemporal_load(row4 + ch * 64);
        PROCR(cv, ch, Tf);
      }
    }
  }
  if (nc > (unsigned)CAND) nc = (unsigned)CAND;  // unreachable safety
  const float smul = exact ? 1.0f : scale;

  // ---- 128-bin histogram over candidates + fused min (sc space) ----
  sh[lane] = 0u;
  sh[lane + 64] = 0u;
  const float binscale = exact ? 0.f : (float)NBIN / Tsel;
  float mn = INFINITY;
  for (unsigned e = lane; e < nc; e += 64) {
    float vv = sc[e].x;
    mn = fminf(mn, vv);
    int b = (int)(vv * binscale);
    b = b < 0 ? 0 : (b > NBIN - 1 ? NBIN - 1 : b);
    atomicAdd(&sh[b], 1u);
  }
  const float minT = wred_min(mn) * smul;

  float v409, v410;  // SCALED order statistics
  if (exact) {
    v409 = ex409;
    v410 = ex410;
  } else {
    // rank-bin locate: 2 bins/lane, wave exclusive scan
    unsigned c2 = sh[2 * lane] + sh[2 * lane + 1];
    unsigned incl = c2;
#pragma unroll
    for (int d = 1; d < 64; d <<= 1) {
      unsigned o = __shfl_up(incl, d, 64);
      if (lane >= d) incl += o;
    }
    unsigned b2 = incl - c2;
    unsigned tb_l = 0, bt_l = 0;
    bool win = (b2 <= (unsigned)RANK && (unsigned)RANK < b2 + c2);
    if (win) {
      unsigned h0 = sh[2 * lane];
      if ((unsigned)RANK < b2 + h0) { tb_l = 2u * lane; bt_l = b2; }
      else { tb_l = 2u * lane + 1u; bt_l = b2 + h0; }
    }
    unsigned long long wm = __ballot(win);
    int wl = (int)__ffsll(wm) - 1;
    if (wl < 0) wl = 0;
    unsigned tb = (unsigned)__shfl((int)tb_l, wl, 64);
    unsigned base_tb = (unsigned)__shfl((int)bt_l, wl, 64);

    // in-bin collect + min-above-bin (raw)
    *scn = 0u;
    float mgt = INFINITY;
    for (unsigned e = lane; e < nc; e += 64) {
      float v = sc[e].x;
      int b = (int)(v * binscale);
      b = b < 0 ? 0 : (b > NBIN - 1 ? NBIN - 1 : b);
      if ((unsigned)b == tb) {
        unsigned p = atomicAdd(scn, 1u);
        if (p < 48u) ssm[p] = v;
      } else if ((unsigned)b > tb) {
        mgt = fminf(mgt, v);
      }
    }
    mgt = wred_min(mgt);
    unsigned cbin = *scn;

    float r409, r410;
    if (cbin <= 48u) {
      float cand = (lane < (int)cbin) ? ssm[lane] : INFINITY;
      unsigned less = 0, eq = 0;
      for (unsigned k = 0; k < cbin; k++) {
        float g = ssm[k];
        less += (g < cand) ? 1u : 0u;
        eq += (g == cand) ? 1u : 0u;
      }
      unsigned gl = base_tb + less;
      bool w9 = (lane < (int)cbin) && gl <= (unsigned)RANK && (unsigned)RANK < gl + eq;
      bool w10 = (lane < (int)cbin) && gl <= (unsigned)(RANK + 1) && (unsigned)(RANK + 1) < gl + eq;
      r409 = wred_min(w9 ? cand : INFINITY);
      float t10 = wred_min(w10 ? cand : INFINITY);
      r410 = isinf(t10) ? mgt : t10;
    } else {
      // pathological clustering fallback: O(nc^2/64) exact
      float a9 = INFINITY, a10 = INFINITY;
      for (unsigned e = lane; e < nc; e += 64) {
        float v = sc[e].x;
        int b = (int)(v * binscale);
        b = b < 0 ? 0 : (b > NBIN - 1 ? NBIN - 1 : b);
        if ((unsigned)b == tb) {
          unsigned less = 0, eq = 0;
          for (unsigned k = 0; k < nc; k++) {
            float g = sc[k].x;
            less += (g < v) ? 1u : 0u;
            eq += (g == v) ? 1u : 0u;
          }
          if (less <= (unsigned)RANK && (unsigned)RANK < less + eq) a9 = v;
          if (less <= (unsigned)(RANK + 1) && (unsigned)(RANK + 1) < less + eq) a10 = v;
        }
      }
      r409 = wred_min(a9);
      float t10 = wred_min(a10);
      r410 = isinf(t10) ? mgt : t10;
    }
    if (isinf(r409)) r409 = mgt;  // unreachable guard
    v409 = r409 * scale;
    v410 = r410 * scale;
  }
  const float thr = 0.5f * v409 + 0.5f * v410;  // jax lerp midpoint, frac=0.5

  // ---- weight pass + in-place compaction (deterministic order) ----
  float psum = 0.f;
  unsigned mq = 0;
  for (unsigned e = lane; e < nc; e += 64) {
    float2 t = sc[e];
    float ts = t.x * smul;
    bool sel = (ts <= thr);
    float w = sel ? __expf(minT - ts) : 0.f;
    psum += w;
    unsigned long long m = __ballot(sel);
    unsigned p = mq + mbcnt64(m);
    if (sel) sc[p] = make_float2(w, t.y);
    mq += (unsigned)__popcll(m);
  }
  mq = (unsigned)__shfl((int)mq, 0, 64);  // lane 0 runs max trips -> true total
  const float denom = wred_sum(psum);
  invd_out = 1.0f / denom;
  const unsigned padded = (mq + 31u) & ~31u;
  for (unsigned e = mq + lane; e < padded; e += 64) sc[e] = make_float2(0.f, __int_as_float(0));
  padded_out = padded;
}

#define GATHER4(SEG, T0, A0, A1, A2, A3, A4, A5, A6, A7)                       \
  do {                                                                         \
    float2 e0 = SEG[(T0) + g];                                                 \
    float2 e1 = SEG[(T0) + 8 + g];                                             \
    float2 e2 = SEG[(T0) + 16 + g];                                            \
    float2 e3 = SEG[(T0) + 24 + g];                                            \
    const uint4 u0 = *reinterpret_cast<const uint4*>(vpb + __float_as_int(e0.y)); \
    const uint4 u1 = *reinterpret_cast<const uint4*>(vpb + __float_as_int(e1.y)); \
    const uint4 u2 = *reinterpret_cast<const uint4*>(vpb + __float_as_int(e2.y)); \
    const uint4 u3 = *reinterpret_cast<const uint4*>(vpb + __float_as_int(e3.y)); \
    float w0 = e0.x, w1 = e1.x, w2 = e2.x, w3 = e3.x;                          \
    A0 = fmaf(w0, bflo(u0.x), A0); A1 = fmaf(w0, bfhi(u0.x), A1);              \
    A2 = fmaf(w0, bflo(u0.y), A2); A3 = fmaf(w0, bfhi(u0.y), A3);              \
    A4 = fmaf(w0, bflo(u0.z), A4); A5 = fmaf(w0, bfhi(u0.z), A5);              \
    A6 = fmaf(w0, bflo(u0.w), A6); A7 = fmaf(w0, bfhi(u0.w), A7);              \
    A0 = fmaf(w1, bflo(u1.x), A0); A1 = fmaf(w1, bfhi(u1.x), A1);              \
    A2 = fmaf(w1, bflo(u1.y), A2); A3 = fmaf(w1, bfhi(u1.y), A3);              \
    A4 = fmaf(w1, bflo(u1.z), A4); A5 = fmaf(w1, bfhi(u1.z), A5);              \
    A6 = fmaf(w1, bflo(u1.w), A6); A7 = fmaf(w1, bfhi(u1.w), A7);              \
    A0 = fmaf(w2, bflo(u2.x), A0); A1 = fmaf(w2, bfhi(u2.x), A1);              \
    A2 = fmaf(w2, bflo(u2.y), A2); A3 = fmaf(w2, bfhi(u2.y), A3);              \
    A4 = fmaf(w2, bflo(u2.z), A4); A5 = fmaf(w2, bfhi(u2.z), A5);              \
    A6 = fmaf(w2, bflo(u2.w), A6); A7 = fmaf(w2, bfhi(u2.w), A7);              \
    A0 = fmaf(w3, bflo(u3.x), A0); A1 = fmaf(w3, bfhi(u3.x), A1);              \
    A2 = fmaf(w3, bflo(u3.y), A2); A3 = fmaf(w3, bfhi(u3.y), A3);              \
    A4 = fmaf(w3, bflo(u3.z), A4); A5 = fmaf(w3, bfhi(u3.z), A5);              \
    A6 = fmaf(w3, bflo(u3.w), A6); A7 = fmaf(w3, bfhi(u3.w), A7);              \
  } while (0)

__global__ __launch_bounds__(128, 3) void attn_kernel(
    const float* __restrict__ m_dist, const __hip_bfloat16* __restrict__ value,
    const float* __restrict__ scales, float* __restrict__ out) {
  const int tid = threadIdx.x;
  const int lane = tid & 63;
  const int wv = tid >> 6;  // 0..1
  // 8192 blocks x 2 waves x 2 rows; bid&7 -> head == XCD (value L2-resident)
  const int bid = blockIdx.x;
  const int h = bid & 7;
  const int qA = (bid >> 3) * 4 + wv * 2;
  const int qB = qA + 1;

  __shared__ float2 s_cand[2][2][CAND];   // 22528 B
  __shared__ unsigned s_hist[2][2][NBIN]; // 2048 B
  __shared__ float s_small[2][2][48];     // 768 B
  __shared__ unsigned s_cnt[2][2];        // 16 B  (~25.4 KB -> 6 blocks/CU)

  float2* scA = s_cand[wv][0];
  float2* scB = s_cand[wv][1];

  const float scale = scales[h];
  const floatx4* rowA =
      reinterpret_cast<const floatx4*>(m_dist + ((size_t)(h * NSEQ + qA)) * NSEQ) + lane;
  const floatx4* rowB =
      reinterpret_cast<const floatx4*>(m_dist + ((size_t)(h * NSEQ + qB)) * NSEQ) + lane;

  // ---- dual HOT stream: 2 chunks deep per row (8 loads in flight) ----
  unsigned ncA = 0, ncB = 0;
  {
    floatx4 aC0 = __builtin_nontemporal_load(rowA + 0 * 64);
    floatx4 aC1 = __builtin_nontemporal_load(rowA + 1 * 64);
    floatx4 bC0 = __builtin_nontemporal_load(rowB + 0 * 64);
    floatx4 bC1 = __builtin_nontemporal_load(rowB + 1 * 64);
    floatx4 aN0 = __builtin_nontemporal_load(rowA + 2 * 64);
    floatx4 aN1 = __builtin_nontemporal_load(rowA + 3 * 64);
    floatx4 bN0 = __builtin_nontemporal_load(rowB + 2 * 64);
    floatx4 bN1 = __builtin_nontemporal_load(rowB + 3 * 64);
    PROCD(aC0, 0, scA, ncA); PROCD(bC0, 0, scB, ncB);
    PROCD(aC1, 1, scA, ncA); PROCD(bC1, 1, scB, ncB);
    aC0 = aN0; aC1 = aN1; bC0 = bN0; bC1 = bN1;
    aN0 = __builtin_nontemporal_load(rowA + 4 * 64);
    aN1 = __builtin_nontemporal_load(rowA + 5 * 64);
    bN0 = __builtin_nontemporal_load(rowB + 4 * 64);
    bN1 = __builtin_nontemporal_load(rowB + 5 * 64);
    PROCD(aC0, 2, scA, ncA); PROCD(bC0, 2, scB, ncB);
    PROCD(aC1, 3, scA, ncA); PROCD(bC1, 3, scB, ncB);
    aC0 = aN0; aC1 = aN1; bC0 = bN0; bC1 = bN1;
    aN0 = __builtin_nontemporal_load(rowA + 6 * 64);
    aN1 = __builtin_nontemporal_load(rowA + 7 * 64);
    bN0 = __builtin_nontemporal_load(rowB + 6 * 64);
    bN1 = __builtin_nontemporal_load(rowB + 7 * 64);
    PROCD(aC0, 4, scA, ncA); PROCD(bC0, 4, scB, ncB);
    PROCD(aC1, 5, scA, ncA); PROCD(bC1, 5, scB, ncB);
    aC0 = aN0; aC1 = aN1; bC0 = bN0; bC1 = bN1;
    aN0 = __builtin_nontemporal_load(rowA + 8 * 64);
    aN1 = __builtin_nontemporal_load(rowA + 9 * 64);
    bN0 = __builtin_nontemporal_load(rowB + 8 * 64);
    bN1 = __builtin_nontemporal_load(rowB + 9 * 64);
    PROCD(aC0, 6, scA, ncA); PROCD(bC0, 6, scB, ncB);
    PROCD(aC1, 7, scA, ncA); PROCD(bC1, 7, scB, ncB);
    aC0 = aN0; aC1 = aN1; bC0 = bN0; bC1 = bN1;
    aN0 = __builtin_nontemporal_load(rowA + 10 * 64);
    aN1 = __builtin_nontemporal_load(rowA + 11 * 64);
    bN0 = __builtin_nontemporal_load(rowB + 10 * 64);
    bN1 = __builtin_nontemporal_load(rowB + 11 * 64);
    PROCD(aC0, 8, scA, ncA); PROCD(bC0, 8, scB, ncB);
    PROCD(aC1, 9, scA, ncA); PROCD(bC1, 9, scB, ncB);
    aC0 = aN0; aC1 = aN1; bC0 = bN0; bC1 = bN1;
    aN0 = __builtin_nontemporal_load(rowA + 12 * 64);
    aN1 = __builtin_nontemporal_load(rowA + 13 * 64);
    bN0 = __builtin_nontemporal_load(rowB + 12 * 64);
    bN1 = __builtin_nontemporal_load(rowB + 13 * 64);
    PROCD(aC0, 10, scA, ncA); PROCD(bC0, 10, scB, ncB);
    PROCD(aC1, 11, scA, ncA); PROCD(bC1, 11, scB, ncB);
    aC0 = aN0; aC1 = aN1; bC0 = bN0; bC1 = bN1;
    aN0 = __builtin_nontemporal_load(rowA + 14 * 64);
    aN1 = __builtin_nontemporal_load(rowA + 15 * 64);
    bN0 = __builtin_nontemporal_load(rowB + 14 * 64);
    bN1 = __builtin_nontemporal_load(rowB + 15 * 64);
    PROCD(aC0, 12, scA, ncA); PROCD(bC0, 12, scB, ncB);
    PROCD(aC1, 13, scA, ncA); PROCD(bC1, 13, scB, ncB);
    aC0 = aN0; aC1 = aN1; bC0 = bN0; bC1 = bN1;
    PROCD(aC0, 14, scA, ncA); PROCD(bC0, 14, scB, ncB);
    PROCD(aC1, 15, scA, ncA); PROCD(bC1, 15, scB, ncB);
  }

  // ---- selection + weights, per row (wave-local) ----
  float invdA, invdB;
  unsigned padA, padB;
  sel_weight(rowA, scale, scA, ncA, s_hist[wv][0], s_small[wv][0], &s_cnt[wv][0],
             lane, invdA, padA);
  sel_weight(rowB, scale, scB, ncB, s_hist[wv][1], s_small[wv][1], &s_cnt[wv][1],
             lane, invdB, padB);

  // ---- dual gather: bf16 rows; 8-lane groups x 16 B; 32 entries/row/iter ----
  const int g = lane >> 3;  // entry group 0..7
  const int c = lane & 7;   // col group: bf16 cols 8c..8c+7
  const char* vpb = (const char*)value + (size_t)h * (NSEQ * 128) + c * 16;
  float x0 = 0.f, x1 = 0.f, x2 = 0.f, x3 = 0.f, x4 = 0.f, x5 = 0.f, x6 = 0.f, x7 = 0.f;
  float y0 = 0.f, y1 = 0.f, y2 = 0.f, y3 = 0.f, y4 = 0.f, y5 = 0.f, y6 = 0.f, y7 = 0.f;
  const unsigned tmax = padA > padB ? padA : padB;
  for (unsigned t0 = 0; t0 < tmax; t0 += 32) {
    if (t0 < padA) GATHER4(scA, t0, x0, x1, x2, x3, x4, x5, x6, x7);
    if (t0 < padB) GATHER4(scB, t0, y0, y1, y2, y3, y4, y5, y6, y7);
  }
  // sum across the 8 entry-groups (lanes differing in bits 3..5)
#pragma unroll
  for (int d = 8; d < 64; d <<= 1) {
    x0 += __shfl_xor(x0, d, 64);
    x1 += __shfl_xor(x1, d, 64);
    x2 += __shfl_xor(x2, d, 64);
    x3 += __shfl_xor(x3, d, 64);
    x4 += __shfl_xor(x4, d, 64);
    x5 += __shfl_xor(x5, d, 64);
    x6 += __shfl_xor(x6, d, 64);
    x7 += __shfl_xor(x7, d, 64);
    y0 += __shfl_xor(y0, d, 64);
    y1 += __shfl_xor(y1, d, 64);
    y2 += __shfl_xor(y2, d, 64);
    y3 += __shfl_xor(y3, d, 64);
    y4 += __shfl_xor(y4, d, 64);
    y5 += __shfl_xor(y5, d, 64);
    y6 += __shfl_xor(y6, d, 64);
    y7 += __shfl_xor(y7, d, 64);
  }

  if (lane < 8) {
    int col = c * 8;
    int bb = col >> 5, kk = col & 31;  // never crosses batch boundary
    {
      float* op = &out[((size_t)bb * NSEQ + qA) * (NH * VD) + (size_t)h * VD + kk];
      float4 lo4 = make_float4(gelu_tanh(x0 * invdA), gelu_tanh(x1 * invdA),
                               gelu_tanh(x2 * invdA), gelu_tanh(x3 * invdA));
      float4 hi4 = make_float4(gelu_tanh(x4 * invdA), gelu_tanh(x5 * invdA),
                               gelu_tanh(x6 * invdA), gelu_tanh(x7 * invdA));
      *reinterpret_cast<float4*>(op) = lo4;
      *reinterpret_cast<float4*>(op + 4) = hi4;
    }
    {
      float* op = &out[((size_t)bb * NSEQ + qB) * (NH * VD) + (size_t)h * VD + kk];
      float4 lo4 = make_float4(gelu_tanh(y0 * invdB), gelu_tanh(y1 * invdB),
                               gelu_tanh(y2 * invdB), gelu_tanh(y3 * invdB));
      float4 hi4 = make_float4(gelu_tanh(y4 * invdB), gelu_tanh(y5 * invdB),
                               gelu_tanh(y6 * invdB), gelu_tanh(y7 * invdB));
      *reinterpret_cast<float4*>(op) = lo4;
      *reinterpret_cast<float4*>(op + 4) = hi4;
    }
  }
}

// ---------------- launch ----------------------------------------------------

extern "C" void kernel_launch(void* const* d_in, const int* in_sizes, int n_in,
                              void* d_out, int out_size, void* d_ws, size_t ws_size,
                              hipStream_t stream) {
  const float* m_dist = (const float*)d_in[0];
  const float* x = (const float*)d_in[1];
  const float* r = (const float*)d_in[2];
  const float* w = (const float*)d_in[3];
  float* out = (float*)d_out;

  __hip_bfloat16* value = (__hip_bfloat16*)d_ws;              // NH*NSEQ*64 bf16 = 4 MB
  float* scales = (float*)((char*)d_ws + (8u << 20));         // +8 MB offset, 8 floats

  value_kernel<<<dim3(NSEQ / 8), dim3(256), 0, stream>>>(x, w, r, value, scales);
  attn_kernel<<<dim3(NH * NSEQ / 4), dim3(128), 0, stream>>>(m_dist, value, scales, out);
}

// Round 19
// 195.832 us; speedup vs baseline: 1.1442x; 1.1442x over previous
//
#include <hip/hip_runtime.h>
#include <hip/hip_bf16.h>
#include <math.h>

#define NH   8
#define NSEQ 4096
#define NB   2
#define HID  256
#define VD   32
#define RANK 409      // 0-indexed; pos = 0.1*(4096-1) = 409.5 -> lerp(s[409],s[410],0.5)
#define NBIN 128      // candidate-space histogram bins (per wave)
#define CAND 704      // per-wave candidate cap (mean 480, sd 20.6); multiple of 32
#define TG   0.1171875f  // raw-space threshold guess (scale>0 -> raw order == scaled order)

typedef float floatx4 __attribute__((ext_vector_type(4)));

__device__ __forceinline__ unsigned mbcnt64(unsigned long long m) {
  return __builtin_amdgcn_mbcnt_hi((unsigned)(m >> 32),
                                   __builtin_amdgcn_mbcnt_lo((unsigned)m, 0u));
}
__device__ __forceinline__ float wred_min(float x) {
#pragma unroll
  for (int d = 32; d; d >>= 1) x = fminf(x, __shfl_xor(x, d, 64));
  return x;
}
__device__ __forceinline__ float wred_max(float x) {
#pragma unroll
  for (int d = 32; d; d >>= 1) x = fmaxf(x, __shfl_xor(x, d, 64));
  return x;
}
__device__ __forceinline__ float wred_sum(float x) {
#pragma unroll
  for (int d = 32; d; d >>= 1) x += __shfl_xor(x, d, 64);
  return x;
}
__device__ __forceinline__ float gelu_tanh(float x) {
  float x3 = x * x * x;
  float inner = 0.7978845608028654f * (x + 0.044715f * x3);
  return 0.5f * x * (1.0f + tanhf(inner));
}
__device__ __forceinline__ float bflo(unsigned u) { return __uint_as_float(u << 16); }
__device__ __forceinline__ float bfhi(unsigned u) { return __uint_as_float(u & 0xFFFF0000u); }

// ---------------- kernel A: value_bf16[h][n][b*32+k] = x @ weight; + scales -

__global__ __launch_bounds__(256) void value_kernel(
    const float* __restrict__ x, const float* __restrict__ w,
    const float* __restrict__ r, __hip_bfloat16* __restrict__ value,
    float* __restrict__ scales) {
  const int tid = threadIdx.x;

  if (blockIdx.x == 0 && tid < NH) {
    double rv = (double)r[tid];
    const float c0 = (float)(0.25 * 3.141592653589793 * (1.0 - 1e-07));
    float s1 = (float)sin(rv);
    float t = c0 * (1.0f + s1);
    scales[tid] = (float)tan((double)t);
  }

  const int n0 = blockIdx.x * 8;
  __shared__ float sx[NB][8][HID];
#pragma unroll
  for (int i = 0; i < 16; i++) {
    int idx = i * 256 + tid;
    int b = idx >> 11;
    int rem = idx & 2047;
    int nn = rem >> 8;
    int j = rem & 255;
    sx[b][nn][j] = x[((size_t)b * NSEQ + n0 + nn) * HID + j];
  }
  __syncthreads();

  const int h = tid >> 5, k = tid & 31;
  float acc[NB][8];
#pragma unroll
  for (int b = 0; b < NB; b++)
#pragma unroll
    for (int nn = 0; nn < 8; nn++) acc[b][nn] = 0.f;

  const float* wp = w + (size_t)h * HID * VD + k;
  for (int j4 = 0; j4 < HID; j4 += 4) {
    float wv0 = wp[(size_t)(j4 + 0) * VD];
    float wv1 = wp[(size_t)(j4 + 1) * VD];
    float wv2 = wp[(size_t)(j4 + 2) * VD];
    float wv3 = wp[(size_t)(j4 + 3) * VD];
#pragma unroll
    for (int b = 0; b < NB; b++) {
#pragma unroll
      for (int nn = 0; nn < 8; nn++) {
        const float4 xv = *reinterpret_cast<const float4*>(&sx[b][nn][j4]);
        float a = acc[b][nn];
        a = fmaf(xv.x, wv0, a);
        a = fmaf(xv.y, wv1, a);
        a = fmaf(xv.z, wv2, a);
        a = fmaf(xv.w, wv3, a);
        acc[b][nn] = a;
      }
    }
  }
#pragma unroll
  for (int b = 0; b < NB; b++)
#pragma unroll
    for (int nn = 0; nn < 8; nn++)
      value[((size_t)h * NSEQ + n0 + nn) * (NB * VD) + b * VD + k] =
          __float2bfloat16(acc[b][nn]);
}

// ---------------- kernel B: ONE WAVE PER ROW, zero __syncthreads ------------
// Selection in RAW space; value table bf16 (128 B rows). Entry byte-offset =
// n*128 -> encode (G<<15)|(lane<<9)|(elem<<7).
// HOT stream fuses candidate-compaction + 128-bin histogram + running min
// (bins over raw [0,TG), compile-time binscale).

#define BSC_HOT ((float)NBIN / TG)

// hot: raw test vs TG + RAW store + fused hist/min
#define PROCH(CV, G)                                                               \
  do {                                                                             \
    const int nb_ = ((G) << 15) | (lane << 9);                                     \
    { bool s = (CV).x <= TG; unsigned long long m = __ballot(s);                   \
      unsigned p = nc + mbcnt64(m);                                                \
      if (s && p < CAND) {                                                         \
        sc[p] = make_float2((CV).x, __int_as_float(nb_));                          \
        int b_ = (int)((CV).x * BSC_HOT); b_ = b_ < 0 ? 0 : (b_ > NBIN - 1 ? NBIN - 1 : b_); \
        atomicAdd(&sh[b_], 1u); mn = fminf(mn, (CV).x);                            \
      }                                                                            \
      nc += (unsigned)__popcll(m); }                                               \
    { bool s = (CV).y <= TG; unsigned long long m = __ballot(s);                   \
      unsigned p = nc + mbcnt64(m);                                                \
      if (s && p < CAND) {                                                         \
        sc[p] = make_float2((CV).y, __int_as_float(nb_ | 128));                    \
        int b_ = (int)((CV).y * BSC_HOT); b_ = b_ < 0 ? 0 : (b_ > NBIN - 1 ? NBIN - 1 : b_); \
        atomicAdd(&sh[b_], 1u); mn = fminf(mn, (CV).y);                            \
      }                                                                            \
      nc += (unsigned)__popcll(m); }                                               \
    { bool s = (CV).z <= TG; unsigned long long m = __ballot(s);                   \
      unsigned p = nc + mbcnt64(m);                                                \
      if (s && p < CAND) {                                                         \
        sc[p] = make_float2((CV).z, __int_as_float(nb_ | 256));                    \
        int b_ = (int)((CV).z * BSC_HOT); b_ = b_ < 0 ? 0 : (b_ > NBIN - 1 ? NBIN - 1 : b_); \
        atomicAdd(&sh[b_], 1u); mn = fminf(mn, (CV).z);                            \
      }                                                                            \
      nc += (unsigned)__popcll(m); }                                               \
    { bool s = (CV).w <= TG; unsigned long long m = __ballot(s);                   \
      unsigned p = nc + mbcnt64(m);                                                \
      if (s && p < CAND) {                                                         \
        sc[p] = make_float2((CV).w, __int_as_float(nb_ | 384));                    \
        int b_ = (int)((CV).w * BSC_HOT); b_ = b_ < 0 ? 0 : (b_ > NBIN - 1 ? NBIN - 1 : b_); \
        atomicAdd(&sh[b_], 1u); mn = fminf(mn, (CV).w);                            \
      }                                                                            \
      nc += (unsigned)__popcll(m); }                                               \
  } while (0)

// cold: raw test + RAW store (no hist)
#define PROCR(CV, G, T)                                                            \
  do {                                                                             \
    const int nb_ = ((G) << 15) | (lane << 9);                                     \
    { bool s = (CV).x <= (T); unsigned long long m = __ballot(s);                  \
      unsigned p = nc + mbcnt64(m);                                                \
      if (s && p < CAND) sc[p] = make_float2((CV).x, __int_as_float(nb_));         \
      nc += (unsigned)__popcll(m); }                                               \
    { bool s = (CV).y <= (T); unsigned long long m = __ballot(s);                  \
      unsigned p = nc + mbcnt64(m);                                                \
      if (s && p < CAND) sc[p] = make_float2((CV).y, __int_as_float(nb_ | 128));   \
      nc += (unsigned)__popcll(m); }                                               \
    { bool s = (CV).z <= (T); unsigned long long m = __ballot(s);                  \
      unsigned p = nc + mbcnt64(m);                                                \
      if (s && p < CAND) sc[p] = make_float2((CV).z, __int_as_float(nb_ | 256));   \
      nc += (unsigned)__popcll(m); }                                               \
    { bool s = (CV).w <= (T); unsigned long long m = __ballot(s);                  \
      unsigned p = nc + mbcnt64(m);                                                \
      if (s && p < CAND) sc[p] = make_float2((CV).w, __int_as_float(nb_ | 384));   \
      nc += (unsigned)__popcll(m); }                                               \
  } while (0)

// cold collapse: scaled test + SCALED store
#define PROCS(CV, G, TS)                                                                  \
  do {                                                                                    \
    const int nb_ = ((G) << 15) | (lane << 9);                                            \
    { float t_ = (CV).x * scale; bool s = t_ <= (TS); unsigned long long m = __ballot(s); \
      unsigned p = nc + mbcnt64(m);                                                       \
      if (s && p < CAND) sc[p] = make_float2(t_, __int_as_float(nb_));                    \
      nc += (unsigned)__popcll(m); }                                                      \
    { float t_ = (CV).y * scale; bool s = t_ <= (TS); unsigned long long m = __ballot(s); \
      unsigned p = nc + mbcnt64(m);                                                       \
      if (s && p < CAND) sc[p] = make_float2(t_, __int_as_float(nb_ | 128));              \
      nc += (unsigned)__popcll(m); }                                                      \
    { float t_ = (CV).z * scale; bool s = t_ <= (TS); unsigned long long m = __ballot(s); \
      unsigned p = nc + mbcnt64(m);                                                       \
      if (s && p < CAND) sc[p] = make_float2(t_, __int_as_float(nb_ | 256));              \
      nc += (unsigned)__popcll(m); }                                                      \
    { float t_ = (CV).w * scale; bool s = t_ <= (TS); unsigned long long m = __ballot(s); \
      unsigned p = nc + mbcnt64(m);                                                       \
      if (s && p < CAND) sc[p] = make_float2(t_, __int_as_float(nb_ | 384));              \
      nc += (unsigned)__popcll(m); }                                                      \
  } while (0)

#define CNT1(U)                                                        \
  do {                                                                 \
    bool s_ = (U) <= Tc;                                               \
    cN += (unsigned)__popcll(__ballot(s_));                            \
    if (s_) vb = fmaxf(vb, (U)); else vs = fminf(vs, (U));             \
  } while (0)

__global__ __launch_bounds__(256, 5) void attn_kernel(
    const float* __restrict__ m_dist, const __hip_bfloat16* __restrict__ value,
    const float* __restrict__ scales, float* __restrict__ out) {
  const int tid = threadIdx.x;
  const int lane = tid & 63;
  const int wv = tid >> 6;
  // 8192 blocks of 4 independent waves; bid&7 -> head == XCD (value L2-resident)
  const int bid = blockIdx.x;
  const int h = bid & 7;
  const int q = (bid >> 3) * 4 + wv;

  __shared__ float2 s_cand[4][CAND];   // 22528 B: per-wave (raw, byteoff)->(w, byteoff)
  __shared__ unsigned s_hist[4][NBIN]; // 2048 B
  __shared__ float s_small[4][48];     // 768 B
  __shared__ unsigned s_cnt[4];        // 16 B

  float2* sc = s_cand[wv];
  unsigned* sh = s_hist[wv];
  float* ssm = s_small[wv];
  unsigned* scn = &s_cnt[wv];

  const float scale = scales[h];
  const floatx4* row4 =
      reinterpret_cast<const floatx4*>(m_dist + ((size_t)(h * NSEQ + q)) * NSEQ) + lane;

  sh[lane] = 0u;
  sh[lane + 64] = 0u;

  // ---- HOT stream: 4 loads in flight; fused compaction + histogram + min ----
  unsigned nc = 0;
  float mn = INFINITY;
  {
    floatx4 c0 = __builtin_nontemporal_load(row4 + 0 * 64);
    floatx4 c1 = __builtin_nontemporal_load(row4 + 1 * 64);
    floatx4 n0 = __builtin_nontemporal_load(row4 + 2 * 64);
    floatx4 n1 = __builtin_nontemporal_load(row4 + 3 * 64);
    PROCH(c0, 0); PROCH(c1, 1);
    c0 = n0; c1 = n1;
    n0 = __builtin_nontemporal_load(row4 + 4 * 64);
    n1 = __builtin_nontemporal_load(row4 + 5 * 64);
    PROCH(c0, 2); PROCH(c1, 3);
    c0 = n0; c1 = n1;
    n0 = __builtin_nontemporal_load(row4 + 6 * 64);
    n1 = __builtin_nontemporal_load(row4 + 7 * 64);
    PROCH(c0, 4); PROCH(c1, 5);
    c0 = n0; c1 = n1;
    n0 = __builtin_nontemporal_load(row4 + 8 * 64);
    n1 = __builtin_nontemporal_load(row4 + 9 * 64);
    PROCH(c0, 6); PROCH(c1, 7);
    c0 = n0; c1 = n1;
    n0 = __builtin_nontemporal_load(row4 + 10 * 64);
    n1 = __builtin_nontemporal_load(row4 + 11 * 64);
    PROCH(c0, 8); PROCH(c1, 9);
    c0 = n0; c1 = n1;
    n0 = __builtin_nontemporal_load(row4 + 12 * 64);
    n1 = __builtin_nontemporal_load(row4 + 13 * 64);
    PROCH(c0, 10); PROCH(c1, 11);
    c0 = n0; c1 = n1;
    n0 = __builtin_nontemporal_load(row4 + 14 * 64);
    n1 = __builtin_nontemporal_load(row4 + 15 * 64);
    PROCH(c0, 12); PROCH(c1, 13);
    c0 = n0; c1 = n1;
    PROCH(c0, 14); PROCH(c1, 15);
  }

  float Tsel = TG;    // raw-space candidate range
  bool exact = false; // collapse path: sc holds SCALED values, ranks known
  float ex409 = 0.f, ex410 = 0.f;
  float binscale = BSC_HOT;

  if (nc < (unsigned)(RANK + 2) || nc > (unsigned)CAND) {
    // ---- cold (wave-local, ~never on this data): count-only bisect ----
    float lo, hi;
    if (nc < (unsigned)(RANK + 2)) { lo = TG; hi = 1.0f; }
    else { lo = 0.f; hi = TG; }
    bool collapse = false, ok = false;
    for (int it = 0; it < 40; ++it) {
      float mid = 0.5f * (lo + hi);
      if (!(mid > lo && mid < hi)) { collapse = true; break; }
      unsigned cN = 0;
      float vb = -INFINITY, vs = INFINITY;
      const float Tc = mid;
#pragma unroll 2
      for (int ch = 0; ch < 16; ++ch) {
        floatx4 cv = __builtin_nontemporal_load(row4 + ch * 64);
        CNT1(cv.x); CNT1(cv.y); CNT1(cv.z); CNT1(cv.w);
      }
      if (cN >= (unsigned)(RANK + 2) && cN <= (unsigned)CAND) { Tsel = mid; ok = true; break; }
      if (cN < (unsigned)(RANK + 2)) lo = mid; else hi = mid;
    }
    if (collapse) {
      unsigned cN = 0;
      float vb = -INFINITY, vs = INFINITY;
      {
        const float Tc = lo;
#pragma unroll 2
        for (int ch = 0; ch < 16; ++ch) {
          floatx4 cv = __builtin_nontemporal_load(row4 + ch * 64);
          CNT1(cv.x); CNT1(cv.y); CNT1(cv.z); CNT1(cv.w);
        }
      }
      vb = wred_max(vb);
      vs = wred_min(vs);
      float s409r, s410r;
      if (cN >= (unsigned)(RANK + 2)) { s409r = vb; s410r = vb; }
      else if (cN == (unsigned)(RANK + 1)) { s409r = vb; s410r = vs; }
      else { s409r = vs; s410r = vs; }
      ex409 = s409r * scale;
      ex410 = s410r * scale;
      exact = true;
      float thrS = 0.5f * ex409 + 0.5f * ex410;
      nc = 0;
#pragma unroll 2
      for (int ch = 0; ch < 16; ++ch) {
        floatx4 cv = __builtin_nontemporal_load(row4 + ch * 64);
        PROCS(cv, ch, thrS);
      }
    } else if (ok) {
      nc = 0;
      const float Tf = Tsel;
#pragma unroll 2
      for (int ch = 0; ch < 16; ++ch) {
        floatx4 cv = __builtin_nontemporal_load(row4 + ch * 64);
        PROCR(cv, ch, Tf);
      }
    }
    if (nc > (unsigned)CAND) nc = (unsigned)CAND;  // unreachable safety
    // rebuild histogram + min over sc (stream's hist is stale)
    sh[lane] = 0u;
    sh[lane + 64] = 0u;
    binscale = exact ? 0.f : (float)NBIN / Tsel;
    mn = INFINITY;
    for (unsigned e = lane; e < nc; e += 64) {
      float vv = sc[e].x;
      mn = fminf(mn, vv);
      int b = (int)(vv * binscale);
      b = b < 0 ? 0 : (b > NBIN - 1 ? NBIN - 1 : b);
      atomicAdd(&sh[b], 1u);
    }
  }
  const float smul = exact ? 1.0f : scale;  // sc values raw (normal) / scaled (exact)
  const float minT = wred_min(mn) * smul;   // scaled global min (monotone fl)

  float v409, v410;  // SCALED order statistics
  if (exact) {
    v409 = ex409;
    v410 = ex410;
  } else {
    // ---- locate rank bin: 2 bins/lane, wave exclusive scan ----
    unsigned c2 = sh[2 * lane] + sh[2 * lane + 1];
    unsigned incl = c2;
#pragma unroll
    for (int d = 1; d < 64; d <<= 1) {
      unsigned o = __shfl_up(incl, d, 64);
      if (lane >= d) incl += o;
    }
    unsigned b2 = incl - c2;
    unsigned tb_l = 0, bt_l = 0;
    bool win = (b2 <= (unsigned)RANK && (unsigned)RANK < b2 + c2);
    if (win) {
      unsigned h0 = sh[2 * lane];
      if ((unsigned)RANK < b2 + h0) { tb_l = 2u * lane; bt_l = b2; }
      else { tb_l = 2u * lane + 1u; bt_l = b2 + h0; }
    }
    unsigned long long wm = __ballot(win);
    int wl = (int)__ffsll(wm) - 1;
    if (wl < 0) wl = 0;  // unreachable guard
    unsigned tb = (unsigned)__shfl((int)tb_l, wl, 64);
    unsigned base_tb = (unsigned)__shfl((int)bt_l, wl, 64);

    // ---- in-bin collect + min-above-bin (raw) ----
    *scn = 0u;
    float mgt = INFINITY;
    for (unsigned e = lane; e < nc; e += 64) {
      float v = sc[e].x;
      int b = (int)(v * binscale);
      b = b < 0 ? 0 : (b > NBIN - 1 ? NBIN - 1 : b);
      if ((unsigned)b == tb) {
        unsigned p = atomicAdd(scn, 1u);
        if (p < 48u) ssm[p] = v;
      } else if ((unsigned)b > tb) {
        mgt = fminf(mgt, v);
      }
    }
    mgt = wred_min(mgt);
    unsigned cbin = *scn;

    // ---- exact raw ranks RANK / RANK+1 ----
    float r409, r410;
    if (cbin <= 48u) {
      float cand = (lane < (int)cbin) ? ssm[lane] : INFINITY;
      unsigned less = 0, eq = 0;
      for (unsigned k = 0; k < cbin; k++) {
        float g = ssm[k];
        less += (g < cand) ? 1u : 0u;
        eq += (g == cand) ? 1u : 0u;
      }
      unsigned gl = base_tb + less;
      bool w9 = (lane < (int)cbin) && gl <= (unsigned)RANK && (unsigned)RANK < gl + eq;
      bool w10 = (lane < (int)cbin) && gl <= (unsigned)(RANK + 1) && (unsigned)(RANK + 1) < gl + eq;
      r409 = wred_min(w9 ? cand : INFINITY);
      float t10 = wred_min(w10 ? cand : INFINITY);
      r410 = isinf(t10) ? mgt : t10;
    } else {
      // pathological clustering fallback: O(nc^2/64) exact (never taken here)
      float a9 = INFINITY, a10 = INFINITY;
      for (unsigned e = lane; e < nc; e += 64) {
        float v = sc[e].x;
        int b = (int)(v * binscale);
        b = b < 0 ? 0 : (b > NBIN - 1 ? NBIN - 1 : b);
        if ((unsigned)b == tb) {
          unsigned less = 0, eq = 0;
          for (unsigned k = 0; k < nc; k++) {
            float g = sc[k].x;
            less += (g < v) ? 1u : 0u;
            eq += (g == v) ? 1u : 0u;
          }
          if (less <= (unsigned)RANK && (unsigned)RANK < less + eq) a9 = v;
          if (less <= (unsigned)(RANK + 1) && (unsigned)(RANK + 1) < less + eq) a10 = v;
        }
      }
      r409 = wred_min(a9);
      float t10 = wred_min(a10);
      r410 = isinf(t10) ? mgt : t10;
    }
    if (isinf(r409)) r409 = mgt;  // unreachable guard
    v409 = r409 * scale;          // fl(sorted_raw[k]*scale) == sorted_scaled[k]
    v410 = r410 * scale;
  }
  const float thr = 0.5f * v409 + 0.5f * v410;  // jax lerp midpoint, frac=0.5

  // ---- weight pass + in-place compaction (fixed order -> deterministic) ----
  float psum = 0.f;
  unsigned mq = 0;
  for (unsigned e = lane; e < nc; e += 64) {
    float2 t = sc[e];
    float ts = t.x * smul;
    bool sel = (ts <= thr);
    float w = sel ? __expf(minT - ts) : 0.f;
    psum += w;
    unsigned long long m = __ballot(sel);
    unsigned p = mq + mbcnt64(m);
    if (sel) sc[p] = make_float2(w, t.y);
    mq += (unsigned)__popcll(m);
  }
  // divergent trip count: lane 0 runs max trips -> true total. Broadcast.
  mq = (unsigned)__shfl((int)mq, 0, 64);
  const float denom = wred_sum(psum);
  const float invd = 1.0f / denom;
  const unsigned padded = (mq + 31u) & ~31u;
  for (unsigned e = mq + lane; e < padded; e += 64) sc[e] = make_float2(0.f, __int_as_float(0));

  // ---- gather: bf16 rows (128 B); 8-lane groups x 16 B; 32 entries/iter ----
  const int g = lane >> 3;       // entry group 0..7
  const int c = lane & 7;        // col group: bf16 cols 8c..8c+7
  const char* vpb = (const char*)value + (size_t)h * (NSEQ * 128) + c * 16;
  float a0 = 0.f, a1 = 0.f, a2 = 0.f, a3 = 0.f, a4 = 0.f, a5 = 0.f, a6 = 0.f, a7 = 0.f;
  for (unsigned t0 = 0; t0 < padded; t0 += 32) {
    float2 e0 = sc[t0 + g];          // 8-lane groups read same addr -> broadcast
    float2 e1 = sc[t0 + 8 + g];
    float2 e2 = sc[t0 + 16 + g];
    float2 e3 = sc[t0 + 24 + g];
    const uint4 u0 = *reinterpret_cast<const uint4*>(vpb + __float_as_int(e0.y));
    const uint4 u1 = *reinterpret_cast<const uint4*>(vpb + __float_as_int(e1.y));
    const uint4 u2 = *reinterpret_cast<const uint4*>(vpb + __float_as_int(e2.y));
    const uint4 u3 = *reinterpret_cast<const uint4*>(vpb + __float_as_int(e3.y));
    float w0 = e0.x, w1 = e1.x, w2 = e2.x, w3 = e3.x;
    a0 = fmaf(w0, bflo(u0.x), a0);
    a1 = fmaf(w0, bfhi(u0.x), a1);
    a2 = fmaf(w0, bflo(u0.y), a2);
    a3 = fmaf(w0, bfhi(u0.y), a3);
    a4 = fmaf(w0, bflo(u0.z), a4);
    a5 = fmaf(w0, bfhi(u0.z), a5);
    a6 = fmaf(w0, bflo(u0.w), a6);
    a7 = fmaf(w0, bfhi(u0.w), a7);
    a0 = fmaf(w1, bflo(u1.x), a0);
    a1 = fmaf(w1, bfhi(u1.x), a1);
    a2 = fmaf(w1, bflo(u1.y), a2);
    a3 = fmaf(w1, bfhi(u1.y), a3);
    a4 = fmaf(w1, bflo(u1.z), a4);
    a5 = fmaf(w1, bfhi(u1.z), a5);
    a6 = fmaf(w1, bflo(u1.w), a6);
    a7 = fmaf(w1, bfhi(u1.w), a7);
    a0 = fmaf(w2, bflo(u2.x), a0);
    a1 = fmaf(w2, bfhi(u2.x), a1);
    a2 = fmaf(w2, bflo(u2.y), a2);
    a3 = fmaf(w2, bfhi(u2.y), a3);
    a4 = fmaf(w2, bflo(u2.z), a4);
    a5 = fmaf(w2, bfhi(u2.z), a5);
    a6 = fmaf(w2, bflo(u2.w), a6);
    a7 = fmaf(w2, bfhi(u2.w), a7);
    a0 = fmaf(w3, bflo(u3.x), a0);
    a1 = fmaf(w3, bfhi(u3.x), a1);
    a2 = fmaf(w3, bflo(u3.y), a2);
    a3 = fmaf(w3, bfhi(u3.y), a3);
    a4 = fmaf(w3, bflo(u3.z), a4);
    a5 = fmaf(w3, bfhi(u3.z), a5);
    a6 = fmaf(w3, bflo(u3.w), a6);
    a7 = fmaf(w3, bfhi(u3.w), a7);
  }
  // sum across the 8 entry-groups (lanes differing in bits 3..5)
#pragma unroll
  for (int d = 8; d < 64; d <<= 1) {
    a0 += __shfl_xor(a0, d, 64);
    a1 += __shfl_xor(a1, d, 64);
    a2 += __shfl_xor(a2, d, 64);
    a3 += __shfl_xor(a3, d, 64);
    a4 += __shfl_xor(a4, d, 64);
    a5 += __shfl_xor(a5, d, 64);
    a6 += __shfl_xor(a6, d, 64);
    a7 += __shfl_xor(a7, d, 64);
  }

  if (lane < 8) {
    // lane c covers cols 8c..8c+7; b = (8c)>>5, k = (8c)&31 (never crosses b)
    int col = c * 8;
    int bb = col >> 5, kk = col & 31;
    float* op = &out[((size_t)bb * NSEQ + q) * (NH * VD) + (size_t)h * VD + kk];
    float4 lo4 = make_float4(gelu_tanh(a0 * invd), gelu_tanh(a1 * invd),
                             gelu_tanh(a2 * invd), gelu_tanh(a3 * invd));
    float4 hi4 = make_float4(gelu_tanh(a4 * invd), gelu_tanh(a5 * invd),
                             gelu_tanh(a6 * invd), gelu_tanh(a7 * invd));
    *reinterpret_cast<float4*>(op) = lo4;
    *reinterpret_cast<float4*>(op + 4) = hi4;
  }
}

// ---------------- launch ----------------------------------------------------

extern "C" void kernel_launch(void* const* d_in, const int* in_sizes, int n_in,
                              void* d_out, int out_size, void* d_ws, size_t ws_size,
                              hipStream_t stream) {
  const float* m_dist = (const float*)d_in[0];
  const float* x = (const float*)d_in[1];
  const float* r = (const float*)d_in[2];
  const float* w = (const float*)d_in[3];
  float* out = (float*)d_out;

  __hip_bfloat16* value = (__hip_bfloat16*)d_ws;              // NH*NSEQ*64 bf16 = 4 MB
  float* scales = (float*)((char*)d_ws + (8u << 20));         // +8 MB offset, 8 floats

  value_kernel<<<dim3(NSEQ / 8), dim3(256), 0, stream>>>(x, w, r, value, scales);
  attn_kernel<<<dim3(NH * NSEQ / 4), dim3(256), 0, stream>>>(m_dist, value, scales, out);
}

// Round 20
// 189.550 us; speedup vs baseline: 1.1821x; 1.0331x over previous
//
#include <hip/hip_runtime.h>
#include <hip/hip_bf16.h>
#include <math.h>

#define NH   8
#define NSEQ 4096
#define NB   2
#define HID  256
#define VD   32
#define RANK 409      // 0-indexed; pos = 0.1*(4096-1) = 409.5 -> lerp(s[409],s[410],0.5)
#define NBIN 128      // candidate-space histogram bins (per wave)
#define CAND 704      // per-wave candidate cap (mean 480, sd 20.6); multiple of 32
#define TG   0.1171875f  // raw-space threshold guess (scale>0 -> raw order == scaled order)

typedef float floatx4 __attribute__((ext_vector_type(4)));

__device__ __forceinline__ unsigned mbcnt64(unsigned long long m) {
  return __builtin_amdgcn_mbcnt_hi((unsigned)(m >> 32),
                                   __builtin_amdgcn_mbcnt_lo((unsigned)m, 0u));
}
__device__ __forceinline__ float wred_min(float x) {
#pragma unroll
  for (int d = 32; d; d >>= 1) x = fminf(x, __shfl_xor(x, d, 64));
  return x;
}
__device__ __forceinline__ float wred_max(float x) {
#pragma unroll
  for (int d = 32; d; d >>= 1) x = fmaxf(x, __shfl_xor(x, d, 64));
  return x;
}
__device__ __forceinline__ float wred_sum(float x) {
#pragma unroll
  for (int d = 32; d; d >>= 1) x += __shfl_xor(x, d, 64);
  return x;
}
__device__ __forceinline__ float gelu_tanh(float x) {
  float x3 = x * x * x;
  float inner = 0.7978845608028654f * (x + 0.044715f * x3);
  return 0.5f * x * (1.0f + tanhf(inner));
}
__device__ __forceinline__ float bflo(unsigned u) { return __uint_as_float(u << 16); }
__device__ __forceinline__ float bfhi(unsigned u) { return __uint_as_float(u & 0xFFFF0000u); }

// ---------------- kernel A: value_bf16[h][n][b*32+k] = x @ weight; + scales -

__global__ __launch_bounds__(256) void value_kernel(
    const float* __restrict__ x, const float* __restrict__ w,
    const float* __restrict__ r, __hip_bfloat16* __restrict__ value,
    float* __restrict__ scales) {
  const int tid = threadIdx.x;

  if (blockIdx.x == 0 && tid < NH) {
    double rv = (double)r[tid];
    const float c0 = (float)(0.25 * 3.141592653589793 * (1.0 - 1e-07));
    float s1 = (float)sin(rv);
    float t = c0 * (1.0f + s1);
    scales[tid] = (float)tan((double)t);
  }

  const int n0 = blockIdx.x * 8;
  __shared__ float sx[NB][8][HID];
#pragma unroll
  for (int i = 0; i < 16; i++) {
    int idx = i * 256 + tid;
    int b = idx >> 11;
    int rem = idx & 2047;
    int nn = rem >> 8;
    int j = rem & 255;
    sx[b][nn][j] = x[((size_t)b * NSEQ + n0 + nn) * HID + j];
  }
  __syncthreads();

  const int h = tid >> 5, k = tid & 31;
  float acc[NB][8];
#pragma unroll
  for (int b = 0; b < NB; b++)
#pragma unroll
    for (int nn = 0; nn < 8; nn++) acc[b][nn] = 0.f;

  const float* wp = w + (size_t)h * HID * VD + k;
  for (int j4 = 0; j4 < HID; j4 += 4) {
    float wv0 = wp[(size_t)(j4 + 0) * VD];
    float wv1 = wp[(size_t)(j4 + 1) * VD];
    float wv2 = wp[(size_t)(j4 + 2) * VD];
    float wv3 = wp[(size_t)(j4 + 3) * VD];
#pragma unroll
    for (int b = 0; b < NB; b++) {
#pragma unroll
      for (int nn = 0; nn < 8; nn++) {
        const float4 xv = *reinterpret_cast<const float4*>(&sx[b][nn][j4]);
        float a = acc[b][nn];
        a = fmaf(xv.x, wv0, a);
        a = fmaf(xv.y, wv1, a);
        a = fmaf(xv.z, wv2, a);
        a = fmaf(xv.w, wv3, a);
        acc[b][nn] = a;
      }
    }
  }
#pragma unroll
  for (int b = 0; b < NB; b++)
#pragma unroll
    for (int nn = 0; nn < 8; nn++)
      value[((size_t)h * NSEQ + n0 + nn) * (NB * VD) + b * VD + k] =
          __float2bfloat16(acc[b][nn]);
}

// ---------------- kernel B: ONE WAVE PER ROW, zero __syncthreads ------------
// Selection in RAW space; value table bf16 (128 B rows). Entry byte-offset =
// n*128 -> encode (G<<15)|(lane<<9)|(elem<<7).

#define PROCR(CV, G, T)                                                            \
  do {                                                                             \
    const int nb_ = ((G) << 15) | (lane << 9);                                     \
    { bool s = (CV).x <= (T); unsigned long long m = __ballot(s);                  \
      unsigned p = nc + mbcnt64(m);                                                \
      if (s && p < CAND) sc[p] = make_float2((CV).x, __int_as_float(nb_));         \
      nc += (unsigned)__popcll(m); }                                               \
    { bool s = (CV).y <= (T); unsigned long long m = __ballot(s);                  \
      unsigned p = nc + mbcnt64(m);                                                \
      if (s && p < CAND) sc[p] = make_float2((CV).y, __int_as_float(nb_ | 128));   \
      nc += (unsigned)__popcll(m); }                                               \
    { bool s = (CV).z <= (T); unsigned long long m = __ballot(s);                  \
      unsigned p = nc + mbcnt64(m);                                                \
      if (s && p < CAND) sc[p] = make_float2((CV).z, __int_as_float(nb_ | 256));   \
      nc += (unsigned)__popcll(m); }                                               \
    { bool s = (CV).w <= (T); unsigned long long m = __ballot(s);                  \
      unsigned p = nc + mbcnt64(m);                                                \
      if (s && p < CAND) sc[p] = make_float2((CV).w, __int_as_float(nb_ | 384));   \
      nc += (unsigned)__popcll(m); }                                               \
  } while (0)

#define PROCS(CV, G, TS)                                                                  \
  do {                                                                                    \
    const int nb_ = ((G) << 15) | (lane << 9);                                            \
    { float t_ = (CV).x * scale; bool s = t_ <= (TS); unsigned long long m = __ballot(s); \
      unsigned p = nc + mbcnt64(m);                                                       \
      if (s && p < CAND) sc[p] = make_float2(t_, __int_as_float(nb_));                    \
      nc += (unsigned)__popcll(m); }                                                      \
    { float t_ = (CV).y * scale; bool s = t_ <= (TS); unsigned long long m = __ballot(s); \
      unsigned p = nc + mbcnt64(m);                                                       \
      if (s && p < CAND) sc[p] = make_float2(t_, __int_as_float(nb_ | 128));              \
      nc += (unsigned)__popcll(m); }                                                      \
    { float t_ = (CV).z * scale; bool s = t_ <= (TS); unsigned long long m = __ballot(s); \
      unsigned p = nc + mbcnt64(m);                                                       \
      if (s && p < CAND) sc[p] = make_float2(t_, __int_as_float(nb_ | 256));              \
      nc += (unsigned)__popcll(m); }                                                      \
    { float t_ = (CV).w * scale; bool s = t_ <= (TS); unsigned long long m = __ballot(s); \
      unsigned p = nc + mbcnt64(m);                                                       \
      if (s && p < CAND) sc[p] = make_float2(t_, __int_as_float(nb_ | 384));              \
      nc += (unsigned)__popcll(m); }                                                      \
  } while (0)

#define CNT1(U)                                                        \
  do {                                                                 \
    bool s_ = (U) <= Tc;                                               \
    cN += (unsigned)__popcll(__ballot(s_));                            \
    if (s_) vb = fmaxf(vb, (U)); else vs = fminf(vs, (U));             \
  } while (0)

__global__ __launch_bounds__(256, 5) void attn_kernel(
    const float* __restrict__ m_dist, const __hip_bfloat16* __restrict__ value,
    const float* __restrict__ scales, float* __restrict__ out) {
  const int tid = threadIdx.x;
  const int lane = tid & 63;
  const int wv = tid >> 6;
  // 8192 blocks of 4 independent waves; bid&7 -> head == XCD (value L2-resident)
  const int bid = blockIdx.x;
  const int h = bid & 7;
  const int q = (bid >> 3) * 4 + wv;

  __shared__ float2 s_cand[4][CAND];   // 22528 B: per-wave (raw, byteoff)->(w, byteoff)
  __shared__ unsigned s_hist[4][NBIN]; // 2048 B
  __shared__ float s_small[4][48];     // 768 B
  __shared__ unsigned s_cnt[4];        // 16 B

  float2* sc = s_cand[wv];
  unsigned* sh = s_hist[wv];
  float* ssm = s_small[wv];
  unsigned* scn = &s_cnt[wv];

  const float scale = scales[h];
  const floatx4* row4 =
      reinterpret_cast<const floatx4*>(m_dist + ((size_t)(h * NSEQ + q)) * NSEQ) + lane;

  // ---- HOT stream: 4 loads in flight, threshold TG, RAW store ----
  unsigned nc = 0;
  {
    floatx4 c0 = __builtin_nontemporal_load(row4 + 0 * 64);
    floatx4 c1 = __builtin_nontemporal_load(row4 + 1 * 64);
    floatx4 n0 = __builtin_nontemporal_load(row4 + 2 * 64);
    floatx4 n1 = __builtin_nontemporal_load(row4 + 3 * 64);
    PROCR(c0, 0, TG); PROCR(c1, 1, TG);
    c0 = n0; c1 = n1;
    n0 = __builtin_nontemporal_load(row4 + 4 * 64);
    n1 = __builtin_nontemporal_load(row4 + 5 * 64);
    PROCR(c0, 2, TG); PROCR(c1, 3, TG);
    c0 = n0; c1 = n1;
    n0 = __builtin_nontemporal_load(row4 + 6 * 64);
    n1 = __builtin_nontemporal_load(row4 + 7 * 64);
    PROCR(c0, 4, TG); PROCR(c1, 5, TG);
    c0 = n0; c1 = n1;
    n0 = __builtin_nontemporal_load(row4 + 8 * 64);
    n1 = __builtin_nontemporal_load(row4 + 9 * 64);
    PROCR(c0, 6, TG); PROCR(c1, 7, TG);
    c0 = n0; c1 = n1;
    n0 = __builtin_nontemporal_load(row4 + 10 * 64);
    n1 = __builtin_nontemporal_load(row4 + 11 * 64);
    PROCR(c0, 8, TG); PROCR(c1, 9, TG);
    c0 = n0; c1 = n1;
    n0 = __builtin_nontemporal_load(row4 + 12 * 64);
    n1 = __builtin_nontemporal_load(row4 + 13 * 64);
    PROCR(c0, 10, TG); PROCR(c1, 11, TG);
    c0 = n0; c1 = n1;
    n0 = __builtin_nontemporal_load(row4 + 14 * 64);
    n1 = __builtin_nontemporal_load(row4 + 15 * 64);
    PROCR(c0, 12, TG); PROCR(c1, 13, TG);
    c0 = n0; c1 = n1;
    PROCR(c0, 14, TG); PROCR(c1, 15, TG);
  }

  float Tsel = TG;    // raw-space candidate range
  bool exact = false; // collapse path: sc holds SCALED values, ranks known
  float ex409 = 0.f, ex410 = 0.f;

  if (nc < (unsigned)(RANK + 2) || nc > (unsigned)CAND) {
    // ---- cold (wave-local, ~never on this data): count-only bisect ----
    float lo, hi;
    if (nc < (unsigned)(RANK + 2)) { lo = TG; hi = 1.0f; }
    else { lo = 0.f; hi = TG; }
    bool collapse = false, ok = false;
    for (int it = 0; it < 40; ++it) {
      float mid = 0.5f * (lo + hi);
      if (!(mid > lo && mid < hi)) { collapse = true; break; }
      unsigned cN = 0;
      float vb = -INFINITY, vs = INFINITY;
      const float Tc = mid;
#pragma unroll 2
      for (int ch = 0; ch < 16; ++ch) {
        floatx4 cv = __builtin_nontemporal_load(row4 + ch * 64);
        CNT1(cv.x); CNT1(cv.y); CNT1(cv.z); CNT1(cv.w);
      }
      if (cN >= (unsigned)(RANK + 2) && cN <= (unsigned)CAND) { Tsel = mid; ok = true; break; }
      if (cN < (unsigned)(RANK + 2)) lo = mid; else hi = mid;
    }
    if (collapse) {
      unsigned cN = 0;
      float vb = -INFINITY, vs = INFINITY;
      {
        const float Tc = lo;
#pragma unroll 2
        for (int ch = 0; ch < 16; ++ch) {
          floatx4 cv = __builtin_nontemporal_load(row4 + ch * 64);
          CNT1(cv.x); CNT1(cv.y); CNT1(cv.z); CNT1(cv.w);
        }
      }
      vb = wred_max(vb);
      vs = wred_min(vs);
      float s409r, s410r;
      if (cN >= (unsigned)(RANK + 2)) { s409r = vb; s410r = vb; }
      else if (cN == (unsigned)(RANK + 1)) { s409r = vb; s410r = vs; }
      else { s409r = vs; s410r = vs; }
      ex409 = s409r * scale;
      ex410 = s410r * scale;
      exact = true;
      float thrS = 0.5f * ex409 + 0.5f * ex410;
      nc = 0;
#pragma unroll 2
      for (int ch = 0; ch < 16; ++ch) {
        floatx4 cv = __builtin_nontemporal_load(row4 + ch * 64);
        PROCS(cv, ch, thrS);
      }
    } else if (ok) {
      nc = 0;
      const float Tf = Tsel;
#pragma unroll 2
      for (int ch = 0; ch < 16; ++ch) {
        floatx4 cv = __builtin_nontemporal_load(row4 + ch * 64);
        PROCR(cv, ch, Tf);
      }
    }
  }
  if (nc > (unsigned)CAND) nc = (unsigned)CAND;  // unreachable safety
  const float smul = exact ? 1.0f : scale;  // sc values raw (normal) / scaled (exact)

  // ---- per-wave 128-bin histogram over candidates + fused min (sc space) ----
  sh[lane] = 0u;
  sh[lane + 64] = 0u;
  const float binscale = exact ? 0.f : (float)NBIN / Tsel;
  float mn = INFINITY;
  for (unsigned e = lane; e < nc; e += 64) {
    float vv = sc[e].x;
    mn = fminf(mn, vv);
    int b = (int)(vv * binscale);
    b = b < 0 ? 0 : (b > NBIN - 1 ? NBIN - 1 : b);
    atomicAdd(&sh[b], 1u);
  }
  const float minT = wred_min(mn) * smul;  // scaled global min (monotone fl)

  float v409, v410;  // SCALED order statistics
  if (exact) {
    v409 = ex409;
    v410 = ex410;
  } else {
    // ---- locate rank bin: 2 bins/lane, wave exclusive scan ----
    unsigned c2 = sh[2 * lane] + sh[2 * lane + 1];
    unsigned incl = c2;
#pragma unroll
    for (int d = 1; d < 64; d <<= 1) {
      unsigned o = __shfl_up(incl, d, 64);
      if (lane >= d) incl += o;
    }
    unsigned b2 = incl - c2;
    unsigned tb_l = 0, bt_l = 0;
    bool win = (b2 <= (unsigned)RANK && (unsigned)RANK < b2 + c2);
    if (win) {
      unsigned h0 = sh[2 * lane];
      if ((unsigned)RANK < b2 + h0) { tb_l = 2u * lane; bt_l = b2; }
      else { tb_l = 2u * lane + 1u; bt_l = b2 + h0; }
    }
    unsigned long long wm = __ballot(win);
    int wl = (int)__ffsll(wm) - 1;
    if (wl < 0) wl = 0;  // unreachable guard
    unsigned tb = (unsigned)__shfl((int)tb_l, wl, 64);
    unsigned base_tb = (unsigned)__shfl((int)bt_l, wl, 64);

    // ---- in-bin collect + min-above-bin (raw) ----
    *scn = 0u;
    float mgt = INFINITY;
    for (unsigned e = lane; e < nc; e += 64) {
      float v = sc[e].x;
      int b = (int)(v * binscale);
      b = b < 0 ? 0 : (b > NBIN - 1 ? NBIN - 1 : b);
      if ((unsigned)b == tb) {
        unsigned p = atomicAdd(scn, 1u);
        if (p < 48u) ssm[p] = v;
      } else if ((unsigned)b > tb) {
        mgt = fminf(mgt, v);
      }
    }
    mgt = wred_min(mgt);
    unsigned cbin = *scn;

    // ---- exact raw ranks RANK / RANK+1 ----
    float r409, r410;
    if (cbin <= 48u) {
      float cand = (lane < (int)cbin) ? ssm[lane] : INFINITY;
      unsigned less = 0, eq = 0;
      for (unsigned k = 0; k < cbin; k++) {
        float g = ssm[k];
        less += (g < cand) ? 1u : 0u;
        eq += (g == cand) ? 1u : 0u;
      }
      unsigned gl = base_tb + less;
      bool w9 = (lane < (int)cbin) && gl <= (unsigned)RANK && (unsigned)RANK < gl + eq;
      bool w10 = (lane < (int)cbin) && gl <= (unsigned)(RANK + 1) && (unsigned)(RANK + 1) < gl + eq;
      r409 = wred_min(w9 ? cand : INFINITY);
      float t10 = wred_min(w10 ? cand : INFINITY);
      r410 = isinf(t10) ? mgt : t10;
    } else {
      // pathological clustering fallback: O(nc^2/64) exact (never taken here)
      float a9 = INFINITY, a10 = INFINITY;
      for (unsigned e = lane; e < nc; e += 64) {
        float v = sc[e].x;
        int b = (int)(v * binscale);
        b = b < 0 ? 0 : (b > NBIN - 1 ? NBIN - 1 : b);
        if ((unsigned)b == tb) {
          unsigned less = 0, eq = 0;
          for (unsigned k = 0; k < nc; k++) {
            float g = sc[k].x;
            less += (g < v) ? 1u : 0u;
            eq += (g == v) ? 1u : 0u;
          }
          if (less <= (unsigned)RANK && (unsigned)RANK < less + eq) a9 = v;
          if (less <= (unsigned)(RANK + 1) && (unsigned)(RANK + 1) < less + eq) a10 = v;
        }
      }
      r409 = wred_min(a9);
      float t10 = wred_min(a10);
      r410 = isinf(t10) ? mgt : t10;
    }
    if (isinf(r409)) r409 = mgt;  // unreachable guard
    v409 = r409 * scale;          // fl(sorted_raw[k]*scale) == sorted_scaled[k]
    v410 = r410 * scale;
  }
  const float thr = 0.5f * v409 + 0.5f * v410;  // jax lerp midpoint, frac=0.5

  // ---- weight pass + in-place compaction (fixed order -> deterministic) ----
  // In-place safe: within an iteration all lane-reads precede the write instr
  // (lockstep wave); cross-iter, write positions < 64*(i+1) <= next read base.
  float psum = 0.f;
  unsigned mq = 0;
  for (unsigned e = lane; e < nc; e += 64) {
    float2 t = sc[e];
    float ts = t.x * smul;  // scaled value
    bool sel = (ts <= thr);
    float w = sel ? __expf(minT - ts) : 0.f;
    psum += w;
    unsigned long long m = __ballot(sel);
    unsigned p = mq + mbcnt64(m);
    if (sel) sc[p] = make_float2(w, t.y);
    mq += (unsigned)__popcll(m);
  }
  // mq is loop-carried and the trip count is divergent (nc % 64 != 0): lanes
  // that skip the final partial iteration miss its popcll. Lane 0 always runs
  // the maximal iteration count -> holds the true total. Broadcast it.
  mq = (unsigned)__shfl((int)mq, 0, 64);
  const float denom = wred_sum(psum);
  const float invd = 1.0f / denom;
  const unsigned padded = (mq + 31u) & ~31u;
  for (unsigned e = mq + lane; e < padded; e += 64) sc[e] = make_float2(0.f, __int_as_float(0));

  // ---- gather: bf16 rows (128 B); 8-lane groups x 16 B; 32 entries/iter ----
  const int g = lane >> 3;       // entry group 0..7
  const int c = lane & 7;        // col group: bf16 cols 8c..8c+7
  const char* vpb = (const char*)value + (size_t)h * (NSEQ * 128) + c * 16;
  float a0 = 0.f, a1 = 0.f, a2 = 0.f, a3 = 0.f, a4 = 0.f, a5 = 0.f, a6 = 0.f, a7 = 0.f;
  for (unsigned t0 = 0; t0 < padded; t0 += 32) {
    float2 e0 = sc[t0 + g];          // 8-lane groups read same addr -> broadcast
    float2 e1 = sc[t0 + 8 + g];
    float2 e2 = sc[t0 + 16 + g];
    float2 e3 = sc[t0 + 24 + g];
    const uint4 u0 = *reinterpret_cast<const uint4*>(vpb + __float_as_int(e0.y));
    const uint4 u1 = *reinterpret_cast<const uint4*>(vpb + __float_as_int(e1.y));
    const uint4 u2 = *reinterpret_cast<const uint4*>(vpb + __float_as_int(e2.y));
    const uint4 u3 = *reinterpret_cast<const uint4*>(vpb + __float_as_int(e3.y));
    float w0 = e0.x, w1 = e1.x, w2 = e2.x, w3 = e3.x;
    a0 = fmaf(w0, bflo(u0.x), a0);
    a1 = fmaf(w0, bfhi(u0.x), a1);
    a2 = fmaf(w0, bflo(u0.y), a2);
    a3 = fmaf(w0, bfhi(u0.y), a3);
    a4 = fmaf(w0, bflo(u0.z), a4);
    a5 = fmaf(w0, bfhi(u0.z), a5);
    a6 = fmaf(w0, bflo(u0.w), a6);
    a7 = fmaf(w0, bfhi(u0.w), a7);
    a0 = fmaf(w1, bflo(u1.x), a0);
    a1 = fmaf(w1, bfhi(u1.x), a1);
    a2 = fmaf(w1, bflo(u1.y), a2);
    a3 = fmaf(w1, bfhi(u1.y), a3);
    a4 = fmaf(w1, bflo(u1.z), a4);
    a5 = fmaf(w1, bfhi(u1.z), a5);
    a6 = fmaf(w1, bflo(u1.w), a6);
    a7 = fmaf(w1, bfhi(u1.w), a7);
    a0 = fmaf(w2, bflo(u2.x), a0);
    a1 = fmaf(w2, bfhi(u2.x), a1);
    a2 = fmaf(w2, bflo(u2.y), a2);
    a3 = fmaf(w2, bfhi(u2.y), a3);
    a4 = fmaf(w2, bflo(u2.z), a4);
    a5 = fmaf(w2, bfhi(u2.z), a5);
    a6 = fmaf(w2, bflo(u2.w), a6);
    a7 = fmaf(w2, bfhi(u2.w), a7);
    a0 = fmaf(w3, bflo(u3.x), a0);
    a1 = fmaf(w3, bfhi(u3.x), a1);
    a2 = fmaf(w3, bflo(u3.y), a2);
    a3 = fmaf(w3, bfhi(u3.y), a3);
    a4 = fmaf(w3, bflo(u3.z), a4);
    a5 = fmaf(w3, bfhi(u3.z), a5);
    a6 = fmaf(w3, bflo(u3.w), a6);
    a7 = fmaf(w3, bfhi(u3.w), a7);
  }
  // sum across the 8 entry-groups (lanes differing in bits 3..5)
#pragma unroll
  for (int d = 8; d < 64; d <<= 1) {
    a0 += __shfl_xor(a0, d, 64);
    a1 += __shfl_xor(a1, d, 64);
    a2 += __shfl_xor(a2, d, 64);
    a3 += __shfl_xor(a3, d, 64);
    a4 += __shfl_xor(a4, d, 64);
    a5 += __shfl_xor(a5, d, 64);
    a6 += __shfl_xor(a6, d, 64);
    a7 += __shfl_xor(a7, d, 64);
  }

  if (lane < 8) {
    // lane c covers cols 8c..8c+7; b = (8c)>>5, k = (8c)&31 (never crosses b)
    int col = c * 8;
    int bb = col >> 5, kk = col & 31;
    float* op = &out[((size_t)bb * NSEQ + q) * (NH * VD) + (size_t)h * VD + kk];
    float4 lo4 = make_float4(gelu_tanh(a0 * invd), gelu_tanh(a1 * invd),
                             gelu_tanh(a2 * invd), gelu_tanh(a3 * invd));
    float4 hi4 = make_float4(gelu_tanh(a4 * invd), gelu_tanh(a5 * invd),
                             gelu_tanh(a6 * invd), gelu_tanh(a7 * invd));
    *reinterpret_cast<float4*>(op) = lo4;
    *reinterpret_cast<float4*>(op + 4) = hi4;
  }
}

// ---------------- launch ----------------------------------------------------

extern "C" void kernel_launch(void* const* d_in, const int* in_sizes, int n_in,
                              void* d_out, int out_size, void* d_ws, size_t ws_size,
                              hipStream_t stream) {
  const float* m_dist = (const float*)d_in[0];
  const float* x = (const float*)d_in[1];
  const float* r = (const float*)d_in[2];
  const float* w = (const float*)d_in[3];
  float* out = (float*)d_out;

  __hip_bfloat16* value = (__hip_bfloat16*)d_ws;              // NH*NSEQ*64 bf16 = 4 MB
  float* scales = (float*)((char*)d_ws + (8u << 20));         // +8 MB offset, 8 floats

  value_kernel<<<dim3(NSEQ / 8), dim3(256), 0, stream>>>(x, w, r, value, scales);
  attn_kernel<<<dim3(NH * NSEQ / 4), dim3(256), 0, stream>>>(m_dist, value, scales, out);
}